// Round 2
// baseline (915.170 us; speedup 1.0000x reference)
//
#include <hip/hip_runtime.h>
#include <hip/hip_bf16.h>
#include <stdint.h>
#include <math.h>

#define NHEAD 16
#define HDIM 64
#define BATCH 4
#define SEQ 2048
#define NROWS (BATCH*SEQ)   /* 8192 */

typedef short bf16x8 __attribute__((ext_vector_type(8)));
typedef float f32x4 __attribute__((ext_vector_type(4)));

__device__ __forceinline__ unsigned short f2bf(float f) {
  unsigned int u = __float_as_uint(f);
  unsigned int r = (u + 0x7fffu + ((u >> 16) & 1u)) >> 16;
  return (unsigned short)r;
}
__device__ __forceinline__ float bf2f(unsigned short h) {
  return __uint_as_float(((unsigned int)h) << 16);
}

typedef const __attribute__((address_space(1))) unsigned int* gas_ptr;
typedef __attribute__((address_space(3))) unsigned int* las_ptr;

__device__ __forceinline__ void gload_lds16(const void* g, void* l) {
  __builtin_amdgcn_global_load_lds((gas_ptr)g, (las_ptr)l, 16, 0, 0);
}

// ---------------- fp32 -> bf16 hi/lo split convert ----------------
__global__ void cvt_split_kernel(const float* __restrict__ in,
                                 unsigned short* __restrict__ hi,
                                 unsigned short* __restrict__ lo, int n4) {
  int stride = gridDim.x * blockDim.x;
  for (int i = blockIdx.x * blockDim.x + threadIdx.x; i < n4; i += stride) {
    float4 v = ((const float4*)in)[i];
    ushort4 h, l;
    h.x = f2bf(v.x); l.x = f2bf(v.x - bf2f(h.x));
    h.y = f2bf(v.y); l.y = f2bf(v.y - bf2f(h.y));
    h.z = f2bf(v.z); l.z = f2bf(v.z - bf2f(h.z));
    h.w = f2bf(v.w); l.w = f2bf(v.w - bf2f(h.w));
    ((ushort4*)hi)[i] = h;
    ((ushort4*)lo)[i] = l;
  }
}

// ---------------- plain fp32 -> bf16 convert ----------------
__global__ void cvt_kernel(const float* __restrict__ in,
                           unsigned short* __restrict__ out, int n4) {
  int stride = gridDim.x * blockDim.x;
  for (int i = blockIdx.x * blockDim.x + threadIdx.x; i < n4; i += stride) {
    float4 v = ((const float4*)in)[i];
    ushort4 o;
    o.x = f2bf(v.x); o.y = f2bf(v.y); o.z = f2bf(v.z); o.w = f2bf(v.w);
    ((ushort4*)out)[i] = o;
  }
}

// ---------------- sincos table [SEQ][32] ----------------
__global__ void sincos_kernel(float2* __restrict__ tab) {
  int idx = blockIdx.x * blockDim.x + threadIdx.x;  // SEQ*32 = 65536
  int s = idx >> 5, i = idx & 31;
  float theta = powf(10000.0f, (float)i / 32.0f);
  float ang = (float)s / theta;
  tab[idx] = make_float2(sinf(ang), cosf(ang));
}

// ---------------- split GEMM for QKV with fused RoPE + scatter epilogue ----
// A[M][K] (hi/lo), B[N][K] (hi/lo); per-tile 3-term MFMA: hh + hl + lh.
// Epilogue: RoPE on q/k cols (fp32), split to Qhi/Qlo/Khi/Klo; V -> Vt bf16.
__global__ __launch_bounds__(256)
void gemm_qkv_split(const unsigned short* __restrict__ Ah,
                    const unsigned short* __restrict__ Al,
                    const unsigned short* __restrict__ Bh,
                    const unsigned short* __restrict__ Bl,
                    const float2* __restrict__ tab,
                    unsigned short* __restrict__ Qhi,
                    unsigned short* __restrict__ Qlo,
                    unsigned short* __restrict__ Khi,
                    unsigned short* __restrict__ Klo,
                    unsigned short* __restrict__ Vt) {
  const int K = 1024, nk = K >> 5;
  __shared__ unsigned short sAh[2][128 * 32];
  __shared__ unsigned short sAl[2][128 * 32];
  __shared__ unsigned short sBh[2][128 * 32];
  __shared__ unsigned short sBl[2][128 * 32];
  const int tid = threadIdx.x;
  const int lane = tid & 63;
  const int wave = tid >> 6;
  const int wr = wave >> 1, wc = wave & 1;
  const long m0 = (long)blockIdx.x * 128;
  const long n0 = (long)blockIdx.y * 128;

  f32x4 acc[4][4] = {};

  const int o0 = tid * 16;
  const int row0_ = o0 >> 6;
  const int colb0 = o0 & 63;

  auto stage = [&](int buf, int kt) {
    const long k0 = (long)kt * 32;
    const char* pAh = (const char*)Ah; const char* pAl = (const char*)Al;
    const char* pBh = (const char*)Bh; const char* pBl = (const char*)Bl;
    gload_lds16(pAh + ((m0 + row0_) * K + k0) * 2 + colb0,      (char*)&sAh[buf][0] + o0);
    gload_lds16(pAh + ((m0 + row0_ + 64) * K + k0) * 2 + colb0, (char*)&sAh[buf][0] + o0 + 4096);
    gload_lds16(pAl + ((m0 + row0_) * K + k0) * 2 + colb0,      (char*)&sAl[buf][0] + o0);
    gload_lds16(pAl + ((m0 + row0_ + 64) * K + k0) * 2 + colb0, (char*)&sAl[buf][0] + o0 + 4096);
    gload_lds16(pBh + ((n0 + row0_) * K + k0) * 2 + colb0,      (char*)&sBh[buf][0] + o0);
    gload_lds16(pBh + ((n0 + row0_ + 64) * K + k0) * 2 + colb0, (char*)&sBh[buf][0] + o0 + 4096);
    gload_lds16(pBl + ((n0 + row0_) * K + k0) * 2 + colb0,      (char*)&sBl[buf][0] + o0);
    gload_lds16(pBl + ((n0 + row0_ + 64) * K + k0) * 2 + colb0, (char*)&sBl[buf][0] + o0 + 4096);
  };

  stage(0, 0);
  __syncthreads();
  int cur = 0;
  const int kq = (lane >> 4) * 8;
  const int rA = wr * 64 + (lane & 15);
  const int rB = wc * 64 + (lane & 15);

  for (int kt = 0; kt < nk; ++kt) {
    if (kt + 1 < nk) stage(cur ^ 1, kt + 1);
    bf16x8 ah[4], al[4], bh[4], bl[4];
#pragma unroll
    for (int m = 0; m < 4; ++m) {
      ah[m] = *(const bf16x8*)&sAh[cur][(rA + m * 16) * 32 + kq];
      al[m] = *(const bf16x8*)&sAl[cur][(rA + m * 16) * 32 + kq];
    }
#pragma unroll
    for (int n = 0; n < 4; ++n) {
      bh[n] = *(const bf16x8*)&sBh[cur][(rB + n * 16) * 32 + kq];
      bl[n] = *(const bf16x8*)&sBl[cur][(rB + n * 16) * 32 + kq];
    }
#pragma unroll
    for (int m = 0; m < 4; ++m)
#pragma unroll
      for (int n = 0; n < 4; ++n) {
        acc[m][n] = __builtin_amdgcn_mfma_f32_16x16x32_bf16(ah[m], bh[n], acc[m][n], 0, 0, 0);
        acc[m][n] = __builtin_amdgcn_mfma_f32_16x16x32_bf16(ah[m], bl[n], acc[m][n], 0, 0, 0);
        acc[m][n] = __builtin_amdgcn_mfma_f32_16x16x32_bf16(al[m], bh[n], acc[m][n], 0, 0, 0);
      }
    __syncthreads();
    cur ^= 1;
  }

  // epilogue: fused RoPE + scatter
  const int lhi = lane >> 4, llo = lane & 15;
  const long rbase = m0 + wr * 64 + (lhi << 2);
  const long cbase = n0 + wc * 64 + llo;
#pragma unroll
  for (int m = 0; m < 4; ++m)
#pragma unroll
    for (int n = 0; n < 4; ++n)
#pragma unroll
      for (int r = 0; r < 4; ++r) {
        int row = (int)(rbase + m * 16 + r);
        int col = (int)(cbase + n * 16);
        float v = acc[m][n][r];
        float p = __shfl_xor(v, 1, 64);   // partner within rope pair (col^1)
        int s = row & 2047, b = row >> 11;
        int h = col / 192, off = col % 192;
        int part = off >> 6, d = off & 63;
        long bh_ = b * 16 + h;
        if (part < 2) {
          float2 sc = tab[s * 32 + (d >> 1)];
          float rot = (d & 1) ? (v * sc.y + p * sc.x) : (v * sc.y - p * sc.x);
          unsigned short hi = f2bf(rot);
          unsigned short lo = f2bf(rot - bf2f(hi));
          long idx = (bh_ * SEQ + s) * 64 + d;
          if (part == 0) { Qhi[idx] = hi; Qlo[idx] = lo; }
          else           { Khi[idx] = hi; Klo[idx] = lo; }
        } else {
          Vt[(bh_ * 64 + d) * SEQ + s] = f2bf(v);
        }
      }
}

// ---------------- GEMM: C[M][N] = A[M][K] * B[N][K]^T (bf16 in, fp32 out) ---
__global__ __launch_bounds__(256)
void gemm_bt_f32(const unsigned short* __restrict__ A,
                 const unsigned short* __restrict__ B,
                 float* __restrict__ C, int M, int N, int K) {
  __shared__ unsigned short sA[2][128 * 32];
  __shared__ unsigned short sB[2][128 * 32];
  const int tid = threadIdx.x;
  const int lane = tid & 63;
  const int wave = tid >> 6;
  const int wr = wave >> 1, wc = wave & 1;
  const long m0 = (long)blockIdx.x * 128;
  const long n0 = (long)blockIdx.y * 128;

  f32x4 acc[4][4] = {};

  const int o0 = tid * 16;
  const int row0_ = o0 >> 6;
  const int colb0 = o0 & 63;

  auto stage = [&](int buf, int kt) {
    const long k0 = (long)kt * 32;
    const char* Ab = (const char*)A;
    const char* Bb = (const char*)B;
    gload_lds16(Ab + ((m0 + row0_) * K + k0) * 2 + colb0,      (char*)&sA[buf][0] + o0);
    gload_lds16(Ab + ((m0 + row0_ + 64) * K + k0) * 2 + colb0, (char*)&sA[buf][0] + o0 + 4096);
    gload_lds16(Bb + ((n0 + row0_) * K + k0) * 2 + colb0,      (char*)&sB[buf][0] + o0);
    gload_lds16(Bb + ((n0 + row0_ + 64) * K + k0) * 2 + colb0, (char*)&sB[buf][0] + o0 + 4096);
  };

  const int nk = K >> 5;
  stage(0, 0);
  __syncthreads();
  int cur = 0;
  const int kq = (lane >> 4) * 8;
  const int rA = wr * 64 + (lane & 15);
  const int rB = wc * 64 + (lane & 15);

  for (int kt = 0; kt < nk; ++kt) {
    if (kt + 1 < nk) stage(cur ^ 1, kt + 1);
    bf16x8 af[4], bfr[4];
#pragma unroll
    for (int m = 0; m < 4; ++m)
      af[m] = *(const bf16x8*)&sA[cur][(rA + m * 16) * 32 + kq];
#pragma unroll
    for (int n = 0; n < 4; ++n)
      bfr[n] = *(const bf16x8*)&sB[cur][(rB + n * 16) * 32 + kq];
#pragma unroll
    for (int m = 0; m < 4; ++m)
#pragma unroll
      for (int n = 0; n < 4; ++n)
        acc[m][n] = __builtin_amdgcn_mfma_f32_16x16x32_bf16(af[m], bfr[n], acc[m][n], 0, 0, 0);
    __syncthreads();
    cur ^= 1;
  }

  const long rbase = m0 + wr * 64 + ((lane >> 4) << 2);
  const long cbase = n0 + wc * 64 + (lane & 15);
#pragma unroll
  for (int m = 0; m < 4; ++m)
#pragma unroll
    for (int n = 0; n < 4; ++n)
#pragma unroll
      for (int r = 0; r < 4; ++r) {
        long row = rbase + m * 16 + r;
        long col = cbase + n * 16;
        C[row * N + col] = acc[m][n][r];
      }
}

// ---------------- flash attention (hi/lo split QK^T) ----------------
__global__ __launch_bounds__(256)
void attn_kernel(const unsigned short* __restrict__ Qhi,
                 const unsigned short* __restrict__ Qlo,
                 const unsigned short* __restrict__ Khi,
                 const unsigned short* __restrict__ Klo,
                 const unsigned short* __restrict__ Vt,
                 unsigned short* __restrict__ AOut) {
  __shared__ unsigned short pbuf[4][16 * 80];
  const int tid = threadIdx.x;
  const int w = tid >> 6, lane = tid & 63;
  const int bh = blockIdx.y, b = bh >> 4, h = bh & 15;
  const int qr0 = blockIdx.x * 64 + w * 16;
  const int lhi = lane >> 4, llo = lane & 15;

  const long qoff = ((long)bh * SEQ + qr0) * 64 + (long)llo * 64 + lhi * 8;
  bf16x8 aq0h = *(const bf16x8*)&Qhi[qoff];
  bf16x8 aq1h = *(const bf16x8*)&Qhi[qoff + 32];
  bf16x8 aq0l = *(const bf16x8*)&Qlo[qoff];
  bf16x8 aq1l = *(const bf16x8*)&Qlo[qoff + 32];

  f32x4 acc[4] = {};
  float mrow[4], lrow[4];
#pragma unroll
  for (int r = 0; r < 4; ++r) { mrow[r] = -INFINITY; lrow[r] = 0.f; }

  for (int kt = 0; kt < SEQ / 64; ++kt) {
    const int key0 = kt * 64;
    const long kbase = ((long)bh * SEQ + key0) * 64;
    f32x4 sc[4];
#pragma unroll
    for (int kf = 0; kf < 4; ++kf) {
      const long ko = kbase + (long)(kf * 16 + llo) * 64 + lhi * 8;
      bf16x8 bk0h = *(const bf16x8*)&Khi[ko];
      bf16x8 bk1h = *(const bf16x8*)&Khi[ko + 32];
      bf16x8 bk0l = *(const bf16x8*)&Klo[ko];
      bf16x8 bk1l = *(const bf16x8*)&Klo[ko + 32];
      f32x4 z = {};
      z = __builtin_amdgcn_mfma_f32_16x16x32_bf16(aq0h, bk0h, z, 0, 0, 0);
      z = __builtin_amdgcn_mfma_f32_16x16x32_bf16(aq1h, bk1h, z, 0, 0, 0);
      z = __builtin_amdgcn_mfma_f32_16x16x32_bf16(aq0h, bk0l, z, 0, 0, 0);
      z = __builtin_amdgcn_mfma_f32_16x16x32_bf16(aq1h, bk1l, z, 0, 0, 0);
      z = __builtin_amdgcn_mfma_f32_16x16x32_bf16(aq0l, bk0h, z, 0, 0, 0);
      z = __builtin_amdgcn_mfma_f32_16x16x32_bf16(aq1l, bk1h, z, 0, 0, 0);
      sc[kf] = z;
    }
    // online softmax (rows = lhi*4+r, cols spread over llo x kf)
    float tmax[4];
#pragma unroll
    for (int r = 0; r < 4; ++r)
      tmax[r] = fmaxf(fmaxf(sc[0][r], sc[1][r]), fmaxf(sc[2][r], sc[3][r]));
#pragma unroll
    for (int off = 1; off < 16; off <<= 1)
#pragma unroll
      for (int r = 0; r < 4; ++r)
        tmax[r] = fmaxf(tmax[r], __shfl_xor(tmax[r], off, 64));
    float alpha[4];
#pragma unroll
    for (int r = 0; r < 4; ++r) {
      float mnew = fmaxf(mrow[r], tmax[r]);
      alpha[r] = __expf(mrow[r] - mnew);
      mrow[r] = mnew;
    }
    float psum[4] = {0.f, 0.f, 0.f, 0.f};
    unsigned short pb[4][4];
#pragma unroll
    for (int kf = 0; kf < 4; ++kf)
#pragma unroll
      for (int r = 0; r < 4; ++r) {
        float p = __expf(sc[kf][r] - mrow[r]);
        psum[r] += p;
        pb[kf][r] = f2bf(p);
      }
#pragma unroll
    for (int off = 1; off < 16; off <<= 1)
#pragma unroll
      for (int r = 0; r < 4; ++r)
        psum[r] += __shfl_xor(psum[r], off, 64);
#pragma unroll
    for (int r = 0; r < 4; ++r) lrow[r] = lrow[r] * alpha[r] + psum[r];
#pragma unroll
    for (int df = 0; df < 4; ++df)
#pragma unroll
      for (int r = 0; r < 4; ++r) acc[df][r] *= alpha[r];

    // P -> LDS (per-wave buffer, stride 80 elems to dodge bank conflicts)
    unsigned short* pw = &pbuf[w][0];
#pragma unroll
    for (int kf = 0; kf < 4; ++kf)
#pragma unroll
      for (int r = 0; r < 4; ++r)
        pw[(lhi * 4 + r) * 80 + kf * 16 + llo] = pb[kf][r];
    bf16x8 pa0 = *(const bf16x8*)&pw[llo * 80 + lhi * 8];
    bf16x8 pa1 = *(const bf16x8*)&pw[llo * 80 + 32 + lhi * 8];

    const unsigned short* Vb = Vt + (long)bh * 64 * SEQ + key0;
#pragma unroll
    for (int df = 0; df < 4; ++df) {
      bf16x8 bv0 = *(const bf16x8*)&Vb[(long)(df * 16 + llo) * SEQ + lhi * 8];
      bf16x8 bv1 = *(const bf16x8*)&Vb[(long)(df * 16 + llo) * SEQ + 32 + lhi * 8];
      acc[df] = __builtin_amdgcn_mfma_f32_16x16x32_bf16(pa0, bv0, acc[df], 0, 0, 0);
      acc[df] = __builtin_amdgcn_mfma_f32_16x16x32_bf16(pa1, bv1, acc[df], 0, 0, 0);
    }
  }

  // epilogue: AOut[b][s][h*64+d] bf16
#pragma unroll
  for (int df = 0; df < 4; ++df)
#pragma unroll
    for (int r = 0; r < 4; ++r) {
      int srow = qr0 + lhi * 4 + r;
      float v = acc[df][r] / lrow[r];
      AOut[((long)b * SEQ + srow) * 1024 + h * 64 + df * 16 + llo] = f2bf(v);
    }
}

// ---------------- launch ----------------
extern "C" void kernel_launch(void* const* d_in, const int* in_sizes, int n_in,
                              void* d_out, int out_size, void* d_ws, size_t ws_size,
                              hipStream_t stream) {
  const float* x     = (const float*)d_in[0];
  const float* w_qkv = (const float*)d_in[1];
  const float* w_out = (const float*)d_in[2];
  float* out = (float*)d_out;
  char* ws = (char*)d_ws;

  unsigned short* xb_hi   = (unsigned short*)(ws + 0);            // 16,777,216
  unsigned short* attnb   = xb_hi;                                // alias (x dead)
  unsigned short* xb_lo   = (unsigned short*)(ws + 16777216);     // 16,777,216
  unsigned short* wqkv_hi = (unsigned short*)(ws + 33554432);     //  6,291,456
  unsigned short* wqkv_lo = (unsigned short*)(ws + 39845888);     //  6,291,456
  unsigned short* woutb   = (unsigned short*)(ws + 46137344);     //  2,097,152
  unsigned short* Qhi     = (unsigned short*)(ws + 48234496);     // 16,777,216
  unsigned short* Qlo     = (unsigned short*)(ws + 65011712);     // 16,777,216
  unsigned short* Khi     = (unsigned short*)(ws + 81788928);     // 16,777,216
  unsigned short* Klo     = (unsigned short*)(ws + 98566144);     // 16,777,216
  unsigned short* Vt      = (unsigned short*)(ws + 115343360);    // 16,777,216
  float2*         tab     = (float2*)(ws + 132120576);            //    524,288

  cvt_split_kernel<<<2048, 256, 0, stream>>>(x, xb_hi, xb_lo, NROWS * 1024 / 4);
  cvt_split_kernel<<<1024, 256, 0, stream>>>(w_qkv, wqkv_hi, wqkv_lo, 3072 * 1024 / 4);
  cvt_kernel<<<512, 256, 0, stream>>>(w_out, woutb, 1024 * 1024 / 4);
  sincos_kernel<<<SEQ * 32 / 256, 256, 0, stream>>>(tab);

  gemm_qkv_split<<<dim3(64, 24), 256, 0, stream>>>(xb_hi, xb_lo, wqkv_hi, wqkv_lo,
                                                   tab, Qhi, Qlo, Khi, Klo, Vt);
  attn_kernel<<<dim3(SEQ / 64, 64), 256, 0, stream>>>(Qhi, Qlo, Khi, Klo, Vt, attnb);
  gemm_bt_f32<<<dim3(64, 8), 256, 0, stream>>>(attnb, woutb, out, NROWS, 1024, 1024);
}

// Round 3
// 257.113 us; speedup vs baseline: 3.5594x; 3.5594x over previous
//
#include <hip/hip_runtime.h>
#include <stdint.h>
#include <math.h>

#define NHEAD 16
#define HDIM 64
#define BATCH 4
#define SEQ 2048
#define NROWS (BATCH*SEQ)   /* 8192 */

typedef _Float16 f16x8 __attribute__((ext_vector_type(8)));
typedef _Float16 f16x4 __attribute__((ext_vector_type(4)));
typedef float f32x4 __attribute__((ext_vector_type(4)));

typedef const __attribute__((address_space(1))) unsigned int* gas_ptr;
typedef __attribute__((address_space(3))) unsigned int* las_ptr;

__device__ __forceinline__ void gload_lds16(const void* g, void* l) {
  __builtin_amdgcn_global_load_lds((gas_ptr)g, (las_ptr)l, 16, 0, 0);
}

// ---------------- fp32 -> fp16 convert ----------------
__global__ void cvt_f16_kernel(const float* __restrict__ in,
                               unsigned short* __restrict__ out, int n4) {
  int stride = gridDim.x * blockDim.x;
  for (int i = blockIdx.x * blockDim.x + threadIdx.x; i < n4; i += stride) {
    float4 v = ((const float4*)in)[i];
    f16x4 h;
    h[0] = (_Float16)v.x; h[1] = (_Float16)v.y;
    h[2] = (_Float16)v.z; h[3] = (_Float16)v.w;
    ((f16x4*)out)[i] = h;
  }
}

// ---------------- sincos table [SEQ][32] ----------------
__global__ void sincos_kernel(float2* __restrict__ tab) {
  int idx = blockIdx.x * blockDim.x + threadIdx.x;  // SEQ*32 = 65536
  int s = idx >> 5, i = idx & 31;
  float theta = powf(10000.0f, (float)i / 32.0f);
  float ang = (float)s / theta;
  tab[idx] = make_float2(sinf(ang), cosf(ang));
}

// ---------------- QKV GEMM (fp16) with fused RoPE + scatter epilogue ------
// A[8192][1024], B[3072][1024] (row-major, = w_qkv[N][K]); C = A*B^T.
// Epilogue: RoPE on q/k (fp32), store Qh/Kh fp16 [bh][s][64]; V -> Vt [bh][64][s].
__global__ __launch_bounds__(256)
void gemm_qkv_f16(const unsigned short* __restrict__ A,
                  const unsigned short* __restrict__ B,
                  const float2* __restrict__ tab,
                  unsigned short* __restrict__ Qh,
                  unsigned short* __restrict__ Kh,
                  unsigned short* __restrict__ Vt) {
  const int K = 1024, N = 3072, nk = K >> 5;
  __shared__ unsigned short sA[2][128 * 32];
  __shared__ unsigned short sB[2][128 * 32];
  const int tid = threadIdx.x;
  const int lane = tid & 63;
  const int wave = tid >> 6;
  const int wr = wave >> 1, wc = wave & 1;
  const long m0 = (long)blockIdx.x * 128;
  const long n0 = (long)blockIdx.y * 128;

  f32x4 acc[4][4] = {};

  const int o0 = tid * 16;
  const int row0_ = o0 >> 6;
  const int colb0 = o0 & 63;

  auto stage = [&](int buf, int kt) {
    const long k0 = (long)kt * 32;
    const char* Ab = (const char*)A;
    const char* Bb = (const char*)B;
    gload_lds16(Ab + ((m0 + row0_) * K + k0) * 2 + colb0,      (char*)&sA[buf][0] + o0);
    gload_lds16(Ab + ((m0 + row0_ + 64) * K + k0) * 2 + colb0, (char*)&sA[buf][0] + o0 + 4096);
    gload_lds16(Bb + ((n0 + row0_) * K + k0) * 2 + colb0,      (char*)&sB[buf][0] + o0);
    gload_lds16(Bb + ((n0 + row0_ + 64) * K + k0) * 2 + colb0, (char*)&sB[buf][0] + o0 + 4096);
  };

  stage(0, 0);
  __syncthreads();
  int cur = 0;
  const int kq = (lane >> 4) * 8;
  const int rA = wr * 64 + (lane & 15);
  const int rB = wc * 64 + (lane & 15);

  for (int kt = 0; kt < nk; ++kt) {
    if (kt + 1 < nk) stage(cur ^ 1, kt + 1);
    f16x8 af[4], bfr[4];
#pragma unroll
    for (int m = 0; m < 4; ++m)
      af[m] = *(const f16x8*)&sA[cur][(rA + m * 16) * 32 + kq];
#pragma unroll
    for (int n = 0; n < 4; ++n)
      bfr[n] = *(const f16x8*)&sB[cur][(rB + n * 16) * 32 + kq];
#pragma unroll
    for (int m = 0; m < 4; ++m)
#pragma unroll
      for (int n = 0; n < 4; ++n)
        acc[m][n] = __builtin_amdgcn_mfma_f32_16x16x32_f16(af[m], bfr[n], acc[m][n], 0, 0, 0);
    __syncthreads();
    cur ^= 1;
  }

  // epilogue: fused RoPE + scatter
  const int lhi = lane >> 4, llo = lane & 15;
  const long rbase = m0 + wr * 64 + (lhi << 2);
  const long cbase = n0 + wc * 64 + llo;
#pragma unroll
  for (int m = 0; m < 4; ++m)
#pragma unroll
    for (int n = 0; n < 4; ++n)
#pragma unroll
      for (int r = 0; r < 4; ++r) {
        int row = (int)(rbase + m * 16 + r);
        int col = (int)(cbase + n * 16);
        float v = acc[m][n][r];
        float p = __shfl_xor(v, 1, 64);   // partner within rope pair (col^1)
        int s = row & 2047, b = row >> 11;
        int h = col / 192, off = col % 192;
        int part = off >> 6, d = off & 63;
        long bh_ = b * 16 + h;
        if (part < 2) {
          float2 sc = tab[s * 32 + (d >> 1)];
          float rot = (d & 1) ? (v * sc.y + p * sc.x) : (v * sc.y - p * sc.x);
          _Float16 hh = (_Float16)rot;
          long idx = (bh_ * SEQ + s) * 64 + d;
          if (part == 0) ((_Float16*)Qh)[idx] = hh;
          else           ((_Float16*)Kh)[idx] = hh;
        } else {
          ((_Float16*)Vt)[(bh_ * 64 + d) * SEQ + s] = (_Float16)v;
        }
      }
}

// ---------------- flash attention (fp16, swapped QK^T, LDS-staged K/V) -----
// Block: 512 thr = 8 waves; wave owns 32 q-rows; block owns 256 q-rows of one bh.
// K/V tiles (64 keys) double-buffered in LDS via gload_lds with XOR swizzle.
__global__ __launch_bounds__(512, 4)
void attn_kernel(const unsigned short* __restrict__ Qh,
                 const unsigned short* __restrict__ Kh,
                 const unsigned short* __restrict__ Vt,
                 unsigned short* __restrict__ AOut) {
  __shared__ unsigned short sK[2][64 * 64];   // [key][dim], 16B-chunk-swizzled
  __shared__ unsigned short sV[2][64 * 64];   // [dim][key], 16B-chunk-swizzled
  __shared__ unsigned short pbuf[8][16 * 72]; // per-wave P tile [q16][key64], stride 72

  const int tid = threadIdx.x;
  const int w = tid >> 6, lane = tid & 63;
  const int llo = lane & 15, lhi = lane >> 4;
  const int bh = blockIdx.y, b = bh >> 4, h = bh & 15;
  const int qw0 = blockIdx.x * 256 + w * 32;

  // Q fragments (B-operand): lane holds Q[col=llo (+m*16)][k=c*32+lhi*8 ..+8)
  f16x8 aq[2][2];
#pragma unroll
  for (int m = 0; m < 2; ++m)
#pragma unroll
    for (int c = 0; c < 2; ++c)
      aq[m][c] = *(const f16x8*)&Qh[((long)bh * SEQ + qw0 + m * 16 + llo) * 64 + c * 32 + lhi * 8];

  f32x4 acc[2][4] = {};
  float mrow[2] = {-INFINITY, -INFINITY};
  float lrow[2] = {0.f, 0.f};

  // staging: thread tid stages 16B chunk tid of each tile, source pre-swizzled
  const int cr = tid >> 3;          // tile row (key for K, dim for V)
  const int cp = tid & 7;           // 16B chunk within 128B row
  const int cps = cp ^ (cr & 7);    // swizzled source chunk
  const long kSrc0 = ((long)bh * SEQ + cr) * 64 + cps * 8;   // + kt*4096
  const long vSrc0 = ((long)bh * 64 + cr) * SEQ + cps * 8;   // + kt*64

  auto stage = [&](int buf, int kt) {
    gload_lds16(&Kh[kSrc0 + (long)kt * 4096], (char*)&sK[buf][0] + tid * 16);
    gload_lds16(&Vt[vSrc0 + (long)kt * 64],   (char*)&sV[buf][0] + tid * 16);
  };

  stage(0, 0);
  __syncthreads();
  int cur = 0;
  unsigned short* pw = &pbuf[w][0];

  for (int kt = 0; kt < SEQ / 64; ++kt) {
    if (kt + 1 < SEQ / 64) stage(cur ^ 1, kt + 1);

    // QK^T (swapped): sc[kf][m], C row = key (lhi*4+r), col = q (llo)
    f32x4 sc[4][2];
#pragma unroll
    for (int kf = 0; kf < 4; ++kf) {
      const int kr = kf * 16 + llo;
      const unsigned short* Kc = &sK[cur][kr * 64];
      f16x8 a0 = *(const f16x8*)&Kc[((0 + lhi) ^ (kr & 7)) * 8];
      f16x8 a1 = *(const f16x8*)&Kc[((4 + lhi) ^ (kr & 7)) * 8];
#pragma unroll
      for (int m = 0; m < 2; ++m) {
        f32x4 z = {};
        z = __builtin_amdgcn_mfma_f32_16x16x32_f16(a0, aq[m][0], z, 0, 0, 0);
        z = __builtin_amdgcn_mfma_f32_16x16x32_f16(a1, aq[m][1], z, 0, 0, 0);
        sc[kf][m] = z;
      }
    }

#pragma unroll
    for (int m = 0; m < 2; ++m) {
      // row max: 16 in-lane values, then reduce across the 4 lhi groups
      float tmax = sc[0][m][0];
#pragma unroll
      for (int kf = 0; kf < 4; ++kf)
#pragma unroll
        for (int r = 0; r < 4; ++r) tmax = fmaxf(tmax, sc[kf][m][r]);
      tmax = fmaxf(tmax, __shfl_xor(tmax, 16, 64));
      tmax = fmaxf(tmax, __shfl_xor(tmax, 32, 64));

      float mnew = fmaxf(mrow[m], tmax);
      float alpha = __expf(mrow[m] - mnew);
      mrow[m] = mnew;

      float psum = 0.f;
#pragma unroll
      for (int kf = 0; kf < 4; ++kf) {
        f16x4 q4;
#pragma unroll
        for (int r = 0; r < 4; ++r) {
          float p = __expf(sc[kf][m][r] - mnew);
          psum += p;
          q4[r] = (_Float16)p;
        }
        *(f16x4*)&pw[llo * 72 + kf * 16 + lhi * 4] = q4;   // P[q=llo][key]
      }
      psum += __shfl_xor(psum, 16, 64);
      psum += __shfl_xor(psum, 32, 64);
      lrow[m] = lrow[m] * alpha + psum;

#pragma unroll
      for (int df = 0; df < 4; ++df) acc[m][df] *= alpha;

      // P B-frags: lane holds P[q=llo][keys c*32+lhi*8 ..+8)
      f16x8 pa0 = *(const f16x8*)&pw[llo * 72 + lhi * 8];
      f16x8 pa1 = *(const f16x8*)&pw[llo * 72 + 32 + lhi * 8];

      // PV: out^T = V^T * P^T ; A = V^T frag, B = P frag
#pragma unroll
      for (int df = 0; df < 4; ++df) {
        const int dr = df * 16 + llo;
        const unsigned short* Vc = &sV[cur][dr * 64];
        f16x8 v0 = *(const f16x8*)&Vc[((0 + lhi) ^ (dr & 7)) * 8];
        f16x8 v1 = *(const f16x8*)&Vc[((4 + lhi) ^ (dr & 7)) * 8];
        acc[m][df] = __builtin_amdgcn_mfma_f32_16x16x32_f16(v0, pa0, acc[m][df], 0, 0, 0);
        acc[m][df] = __builtin_amdgcn_mfma_f32_16x16x32_f16(v1, pa1, acc[m][df], 0, 0, 0);
      }
    }
    __syncthreads();
    cur ^= 1;
  }

  // epilogue: out[q][d], q = qw0+m*16+llo, d = df*16+lhi*4+r
#pragma unroll
  for (int m = 0; m < 2; ++m) {
    float inv = 1.f / lrow[m];
#pragma unroll
    for (int df = 0; df < 4; ++df) {
      f16x4 o;
#pragma unroll
      for (int r = 0; r < 4; ++r) o[r] = (_Float16)(acc[m][df][r] * inv);
      int q = qw0 + m * 16 + llo;
      int d = df * 16 + lhi * 4;
      *(f16x4*)&AOut[((long)b * SEQ + q) * 1024 + h * 64 + d] = o;
    }
  }
}

// ---------------- out-proj GEMM: C[M][N] = A[M][K] * B[N][K]^T, fp32 out ---
__global__ __launch_bounds__(256)
void gemm_out_f16(const unsigned short* __restrict__ A,
                  const unsigned short* __restrict__ B,
                  float* __restrict__ C, int M, int N, int K) {
  __shared__ unsigned short sA[2][128 * 32];
  __shared__ unsigned short sB[2][128 * 32];
  const int tid = threadIdx.x;
  const int lane = tid & 63;
  const int wave = tid >> 6;
  const int wr = wave >> 1, wc = wave & 1;
  const long m0 = (long)blockIdx.x * 128;
  const long n0 = (long)blockIdx.y * 128;

  f32x4 acc[4][4] = {};

  const int o0 = tid * 16;
  const int row0_ = o0 >> 6;
  const int colb0 = o0 & 63;

  auto stage = [&](int buf, int kt) {
    const long k0 = (long)kt * 32;
    const char* Ab = (const char*)A;
    const char* Bb = (const char*)B;
    gload_lds16(Ab + ((m0 + row0_) * K + k0) * 2 + colb0,      (char*)&sA[buf][0] + o0);
    gload_lds16(Ab + ((m0 + row0_ + 64) * K + k0) * 2 + colb0, (char*)&sA[buf][0] + o0 + 4096);
    gload_lds16(Bb + ((n0 + row0_) * K + k0) * 2 + colb0,      (char*)&sB[buf][0] + o0);
    gload_lds16(Bb + ((n0 + row0_ + 64) * K + k0) * 2 + colb0, (char*)&sB[buf][0] + o0 + 4096);
  };

  const int nk = K >> 5;
  stage(0, 0);
  __syncthreads();
  int cur = 0;
  const int kq = (lane >> 4) * 8;
  const int rA = wr * 64 + (lane & 15);
  const int rB = wc * 64 + (lane & 15);

  for (int kt = 0; kt < nk; ++kt) {
    if (kt + 1 < nk) stage(cur ^ 1, kt + 1);
    f16x8 af[4], bfr[4];
#pragma unroll
    for (int m = 0; m < 4; ++m)
      af[m] = *(const f16x8*)&sA[cur][(rA + m * 16) * 32 + kq];
#pragma unroll
    for (int n = 0; n < 4; ++n)
      bfr[n] = *(const f16x8*)&sB[cur][(rB + n * 16) * 32 + kq];
#pragma unroll
    for (int m = 0; m < 4; ++m)
#pragma unroll
      for (int n = 0; n < 4; ++n)
        acc[m][n] = __builtin_amdgcn_mfma_f32_16x16x32_f16(af[m], bfr[n], acc[m][n], 0, 0, 0);
    __syncthreads();
    cur ^= 1;
  }

  const long rbase = m0 + wr * 64 + ((lane >> 4) << 2);
  const long cbase = n0 + wc * 64 + (lane & 15);
#pragma unroll
  for (int m = 0; m < 4; ++m)
#pragma unroll
    for (int n = 0; n < 4; ++n)
#pragma unroll
      for (int r = 0; r < 4; ++r) {
        long row = rbase + m * 16 + r;
        long col = cbase + n * 16;
        C[row * N + col] = acc[m][n][r];
      }
}

// ---------------- launch ----------------
extern "C" void kernel_launch(void* const* d_in, const int* in_sizes, int n_in,
                              void* d_out, int out_size, void* d_ws, size_t ws_size,
                              hipStream_t stream) {
  const float* x     = (const float*)d_in[0];
  const float* w_qkv = (const float*)d_in[1];
  const float* w_out = (const float*)d_in[2];
  float* out = (float*)d_out;
  char* ws = (char*)d_ws;

  unsigned short* xb    = (unsigned short*)(ws + 0);           // 16 MB
  unsigned short* attnb = xb;                                  // alias (x dead)
  unsigned short* wqkvb = (unsigned short*)(ws + 16777216);    //  6 MB
  unsigned short* woutb = (unsigned short*)(ws + 23068672);    //  2 MB
  unsigned short* Qh    = (unsigned short*)(ws + 25165824);    // 16 MB
  unsigned short* Kh    = (unsigned short*)(ws + 41943040);    // 16 MB
  unsigned short* Vt    = (unsigned short*)(ws + 58720256);    // 16 MB
  float2*         tab   = (float2*)(ws + 75497472);            // 512 KB

  cvt_f16_kernel<<<2048, 256, 0, stream>>>(x, xb, NROWS * 1024 / 4);
  cvt_f16_kernel<<<1024, 256, 0, stream>>>(w_qkv, wqkvb, 3072 * 1024 / 4);
  cvt_f16_kernel<<<512, 256, 0, stream>>>(w_out, woutb, 1024 * 1024 / 4);
  sincos_kernel<<<SEQ * 32 / 256, 256, 0, stream>>>(tab);

  gemm_qkv_f16<<<dim3(64, 24), 256, 0, stream>>>(xb, wqkvb, tab, Qh, Kh, Vt);
  attn_kernel<<<dim3(SEQ / 256, 64), 512, 0, stream>>>(Qh, Kh, Vt, attnb);
  gemm_out_f16<<<dim3(64, 8), 256, 0, stream>>>(attnb, woutb, out, NROWS, 1024, 1024);
}

// Round 5
// 253.818 us; speedup vs baseline: 3.6056x; 1.0130x over previous
//
#include <hip/hip_runtime.h>
#include <stdint.h>
#include <math.h>

#define NHEAD 16
#define HDIM 64
#define BATCH 4
#define SEQ 2048
#define NROWS (BATCH*SEQ)   /* 8192 */
#define LOG2E 1.4426950408889634f

typedef _Float16 f16x8 __attribute__((ext_vector_type(8)));
typedef _Float16 f16x4 __attribute__((ext_vector_type(4)));
typedef __fp16 h16x2 __attribute__((ext_vector_type(2)));
typedef float f32x4 __attribute__((ext_vector_type(4)));

typedef const __attribute__((address_space(1))) unsigned int* gas_ptr;
typedef __attribute__((address_space(3))) unsigned int* las_ptr;

__device__ __forceinline__ void gload_lds16(const void* g, void* l) {
  __builtin_amdgcn_global_load_lds((gas_ptr)g, (las_ptr)l, 16, 0, 0);
}

__device__ __forceinline__ float exp2_fast(float x) {
  float r; asm("v_exp_f32 %0, %1" : "=v"(r) : "v"(x)); return r;
}

// ---------------- fp32 -> fp16 convert ----------------
__global__ void cvt_f16_kernel(const float* __restrict__ in,
                               unsigned short* __restrict__ out, int n4) {
  int stride = gridDim.x * blockDim.x;
  for (int i = blockIdx.x * blockDim.x + threadIdx.x; i < n4; i += stride) {
    float4 v = ((const float4*)in)[i];
    f16x4 h;
    h[0] = (_Float16)v.x; h[1] = (_Float16)v.y;
    h[2] = (_Float16)v.z; h[3] = (_Float16)v.w;
    ((f16x4*)out)[i] = h;
  }
}

// ---------------- sincos table [SEQ][32] ----------------
__global__ void sincos_kernel(float2* __restrict__ tab) {
  int idx = blockIdx.x * blockDim.x + threadIdx.x;  // SEQ*32 = 65536
  int s = idx >> 5, i = idx & 31;
  float theta = powf(10000.0f, (float)i / 32.0f);
  float ang = (float)s / theta;
  tab[idx] = make_float2(sinf(ang), cosf(ang));
}

// ---------------- QKV GEMM (fp16) with fused RoPE + scatter epilogue ------
// A[8192][1024], B[3072][1024] (row-major, = w_qkv[N][K]); C = A*B^T.
// Epilogue: RoPE (fp32); Q scaled by log2(e) for exp2-domain softmax.
__global__ __launch_bounds__(256)
void gemm_qkv_f16(const unsigned short* __restrict__ A,
                  const unsigned short* __restrict__ B,
                  const float2* __restrict__ tab,
                  unsigned short* __restrict__ Qh,
                  unsigned short* __restrict__ Kh,
                  unsigned short* __restrict__ Vt) {
  const int K = 1024, N = 3072, nk = K >> 5;
  __shared__ unsigned short sA[2][128 * 32];
  __shared__ unsigned short sB[2][128 * 32];
  const int tid = threadIdx.x;
  const int lane = tid & 63;
  const int wave = tid >> 6;
  const int wr = wave >> 1, wc = wave & 1;
  const long m0 = (long)blockIdx.x * 128;
  const long n0 = (long)blockIdx.y * 128;

  f32x4 acc[4][4] = {};

  const int o0 = tid * 16;
  const int row0_ = o0 >> 6;
  const int colb0 = o0 & 63;

  auto stage = [&](int buf, int kt) {
    const long k0 = (long)kt * 32;
    const char* Ab = (const char*)A;
    const char* Bb = (const char*)B;
    gload_lds16(Ab + ((m0 + row0_) * K + k0) * 2 + colb0,      (char*)&sA[buf][0] + o0);
    gload_lds16(Ab + ((m0 + row0_ + 64) * K + k0) * 2 + colb0, (char*)&sA[buf][0] + o0 + 4096);
    gload_lds16(Bb + ((n0 + row0_) * K + k0) * 2 + colb0,      (char*)&sB[buf][0] + o0);
    gload_lds16(Bb + ((n0 + row0_ + 64) * K + k0) * 2 + colb0, (char*)&sB[buf][0] + o0 + 4096);
  };

  stage(0, 0);
  __syncthreads();
  int cur = 0;
  const int kq = (lane >> 4) * 8;
  const int rA = wr * 64 + (lane & 15);
  const int rB = wc * 64 + (lane & 15);

  for (int kt = 0; kt < nk; ++kt) {
    if (kt + 1 < nk) stage(cur ^ 1, kt + 1);
    f16x8 af[4], bfr[4];
#pragma unroll
    for (int m = 0; m < 4; ++m)
      af[m] = *(const f16x8*)&sA[cur][(rA + m * 16) * 32 + kq];
#pragma unroll
    for (int n = 0; n < 4; ++n)
      bfr[n] = *(const f16x8*)&sB[cur][(rB + n * 16) * 32 + kq];
#pragma unroll
    for (int m = 0; m < 4; ++m)
#pragma unroll
      for (int n = 0; n < 4; ++n)
        acc[m][n] = __builtin_amdgcn_mfma_f32_16x16x32_f16(af[m], bfr[n], acc[m][n], 0, 0, 0);
    __syncthreads();
    cur ^= 1;
  }

  // epilogue: fused RoPE + scatter
  const int lhi = lane >> 4, llo = lane & 15;
  const long rbase = m0 + wr * 64 + (lhi << 2);
  const long cbase = n0 + wc * 64 + llo;
#pragma unroll
  for (int m = 0; m < 4; ++m)
#pragma unroll
    for (int n = 0; n < 4; ++n)
#pragma unroll
      for (int r = 0; r < 4; ++r) {
        int row = (int)(rbase + m * 16 + r);
        int col = (int)(cbase + n * 16);
        float v = acc[m][n][r];
        float p = __shfl_xor(v, 1, 64);   // partner within rope pair (col^1)
        int s = row & 2047, b = row >> 11;
        int h = col / 192, off = col % 192;
        int part = off >> 6, d = off & 63;
        long bh_ = b * 16 + h;
        if (part < 2) {
          float2 sc = tab[s * 32 + (d >> 1)];
          float rot = (d & 1) ? (v * sc.y + p * sc.x) : (v * sc.y - p * sc.x);
          long idx = (bh_ * SEQ + s) * 64 + d;
          if (part == 0) ((_Float16*)Qh)[idx] = (_Float16)(rot * LOG2E);
          else           ((_Float16*)Kh)[idx] = (_Float16)rot;
        } else {
          ((_Float16*)Vt)[(bh_ * 64 + d) * SEQ + s] = (_Float16)v;
        }
      }
}

// ---------------- flash attention (fp16, swapped QK^T, exp2-domain) -------
// Block: 512 thr = 8 waves; wave owns 32 q-rows; block owns 256 q-rows of one bh.
// K/V tiles (64 keys) double-buffered in LDS via gload_lds with XOR swizzle.
// Softmax: defer-max (THR=8 log2), l via ones-MFMA, pkrtz P conversion.
__global__ __launch_bounds__(512, 4)
void attn_kernel(const unsigned short* __restrict__ Qh,
                 const unsigned short* __restrict__ Kh,
                 const unsigned short* __restrict__ Vt,
                 unsigned short* __restrict__ AOut) {
  __shared__ unsigned short sK[2][64 * 64];   // [key][dim], 16B-chunk-swizzled
  __shared__ unsigned short sV[2][64 * 64];   // [dim][key], 16B-chunk-swizzled
  __shared__ unsigned short pbuf[8][16 * 72]; // per-wave P tile [q16][key64]

  const int tid = threadIdx.x;
  const int w = tid >> 6, lane = tid & 63;
  const int llo = lane & 15, lhi = lane >> 4;
  const int bh = blockIdx.y, b = bh >> 4, h = bh & 15;
  const int qw0 = blockIdx.x * 256 + w * 32;

  // Q fragments (B-operand): lane holds Q[col=llo (+m*16)][k=c*32+lhi*8 ..+8)
  f16x8 aq[2][2];
#pragma unroll
  for (int m = 0; m < 2; ++m)
#pragma unroll
    for (int c = 0; c < 2; ++c)
      aq[m][c] = *(const f16x8*)&Qh[((long)bh * SEQ + qw0 + m * 16 + llo) * 64 + c * 32 + lhi * 8];

  f32x4 acc[2][4] = {};
  f32x4 accl[2] = {};                  // l accumulator (ones-MFMA row sums)
  float mrow[2] = {-INFINITY, -INFINITY};

  // hoisted LDS read offsets (elements); V formula == K formula
  int koff0[4], koff1[4];
#pragma unroll
  for (int kf = 0; kf < 4; ++kf) {
    int kr = kf * 16 + llo;
    koff0[kf] = kr * 64 + ((0 + lhi) ^ (kr & 7)) * 8;
    koff1[kf] = kr * 64 + ((4 + lhi) ^ (kr & 7)) * 8;
  }
  const int pwbase = llo * 72;
  const int pr0 = llo * 72 + lhi * 8, pr1 = pr0 + 32;

  f16x8 vones;
#pragma unroll
  for (int j = 0; j < 8; ++j) vones[j] = (_Float16)1.0f;

  // staging: thread tid stages 16B chunk tid of each tile, source pre-swizzled
  const int cr = tid >> 3;          // tile row (key for K, dim for V)
  const int cp = tid & 7;           // 16B chunk within 128B row
  const int cps = cp ^ (cr & 7);    // swizzled source chunk
  const long kSrc0 = ((long)bh * SEQ + cr) * 64 + cps * 8;   // + kt*4096
  const long vSrc0 = ((long)bh * 64 + cr) * SEQ + cps * 8;   // + kt*64

  auto stage = [&](int buf, int kt) {
    gload_lds16(&Kh[kSrc0 + (long)kt * 4096], (char*)&sK[buf][0] + tid * 16);
    gload_lds16(&Vt[vSrc0 + (long)kt * 64],   (char*)&sV[buf][0] + tid * 16);
  };

  stage(0, 0);
  __syncthreads();
  unsigned short* pw = &pbuf[w][0];

#pragma unroll 2
  for (int kt = 0; kt < SEQ / 64; ++kt) {
    const int cur = kt & 1;
    if (kt + 1 < SEQ / 64) stage(cur ^ 1, kt + 1);
    const unsigned short* Kb = &sK[cur][0];
    const unsigned short* Vb = &sV[cur][0];

    // QK^T (swapped): C row = key (lhi*4+r), col = q (llo); scores in log2 units
    f32x4 sc[4][2];
#pragma unroll
    for (int kf = 0; kf < 4; ++kf) {
      f16x8 a0 = *(const f16x8*)&Kb[koff0[kf]];
      f16x8 a1 = *(const f16x8*)&Kb[koff1[kf]];
#pragma unroll
      for (int m = 0; m < 2; ++m) {
        f32x4 z = {};
        z = __builtin_amdgcn_mfma_f32_16x16x32_f16(a0, aq[m][0], z, 0, 0, 0);
        z = __builtin_amdgcn_mfma_f32_16x16x32_f16(a1, aq[m][1], z, 0, 0, 0);
        sc[kf][m] = z;
      }
    }

#pragma unroll
    for (int m = 0; m < 2; ++m) {
      // row max: 16 in-lane (max3-friendly chains), then across 4 lhi groups
      float t0 = fmaxf(fmaxf(fmaxf(sc[0][m][0], sc[0][m][1]), sc[0][m][2]), sc[0][m][3]);
      float t1 = fmaxf(fmaxf(fmaxf(sc[1][m][0], sc[1][m][1]), sc[1][m][2]), sc[1][m][3]);
      float t2 = fmaxf(fmaxf(fmaxf(sc[2][m][0], sc[2][m][1]), sc[2][m][2]), sc[2][m][3]);
      float t3 = fmaxf(fmaxf(fmaxf(sc[3][m][0], sc[3][m][1]), sc[3][m][2]), sc[3][m][3]);
      float tmax = fmaxf(fmaxf(t0, t1), fmaxf(t2, t3));
      tmax = fmaxf(tmax, __shfl_xor(tmax, 16, 64));
      tmax = fmaxf(tmax, __shfl_xor(tmax, 32, 64));

      // defer-max: only rescale when max grew by > 8 (log2) somewhere in wave
      if (__any(tmax > mrow[m] + 8.0f)) {
        float mnew = fmaxf(mrow[m], tmax);
        float al = exp2_fast(mrow[m] - mnew);
        mrow[m] = mnew;
#pragma unroll
        for (int df = 0; df < 4; ++df) acc[m][df] *= al;
        accl[m] *= al;
      }
      const float mr = mrow[m];

      // P = 2^(s - m), packed to f16, one b64 LDS write per kf
#pragma unroll
      for (int kf = 0; kf < 4; ++kf) {
        float p0 = exp2_fast(sc[kf][m][0] - mr);
        float p1 = exp2_fast(sc[kf][m][1] - mr);
        float p2 = exp2_fast(sc[kf][m][2] - mr);
        float p3 = exp2_fast(sc[kf][m][3] - mr);
        h16x2 plo = __builtin_amdgcn_cvt_pkrtz(p0, p1);
        h16x2 phi = __builtin_amdgcn_cvt_pkrtz(p2, p3);
        uint2 wv;
        wv.x = __builtin_bit_cast(unsigned int, plo);
        wv.y = __builtin_bit_cast(unsigned int, phi);
        *(uint2*)&pw[pwbase + kf * 16 + lhi * 4] = wv;   // P[q=llo][key]
      }

      // P B-frags: lane holds P[q=llo][keys c*32+lhi*8 ..+8)
      f16x8 pa0 = *(const f16x8*)&pw[pr0];
      f16x8 pa1 = *(const f16x8*)&pw[pr1];

      // l via ones-MFMA (row sums of P land in every output row)
      accl[m] = __builtin_amdgcn_mfma_f32_16x16x32_f16(vones, pa0, accl[m], 0, 0, 0);
      accl[m] = __builtin_amdgcn_mfma_f32_16x16x32_f16(vones, pa1, accl[m], 0, 0, 0);

      // PV: out^T = V^T * P^T ; A = V^T frag (same offsets as K), B = P frag
#pragma unroll
      for (int df = 0; df < 4; ++df) {
        f16x8 v0 = *(const f16x8*)&Vb[koff0[df]];
        f16x8 v1 = *(const f16x8*)&Vb[koff1[df]];
        acc[m][df] = __builtin_amdgcn_mfma_f32_16x16x32_f16(v0, pa0, acc[m][df], 0, 0, 0);
        acc[m][df] = __builtin_amdgcn_mfma_f32_16x16x32_f16(v1, pa1, acc[m][df], 0, 0, 0);
      }
    }
    __syncthreads();
  }

  // epilogue: out[q][d], q = qw0+m*16+llo, d = df*16+lhi*4+r
#pragma unroll
  for (int m = 0; m < 2; ++m) {
    float inv = 1.f / accl[m][0];
#pragma unroll
    for (int df = 0; df < 4; ++df) {
      f16x4 o;
#pragma unroll
      for (int r = 0; r < 4; ++r) o[r] = (_Float16)(acc[m][df][r] * inv);
      int q = qw0 + m * 16 + llo;
      int d = df * 16 + lhi * 4;
      *(f16x4*)&AOut[((long)b * SEQ + q) * 1024 + h * 64 + d] = o;
    }
  }
}

// ---------------- out-proj GEMM: C[M][N] = A[M][K] * B[N][K]^T, fp32 out ---
__global__ __launch_bounds__(256)
void gemm_out_f16(const unsigned short* __restrict__ A,
                  const unsigned short* __restrict__ B,
                  float* __restrict__ C, int M, int N, int K) {
  __shared__ unsigned short sA[2][128 * 32];
  __shared__ unsigned short sB[2][128 * 32];
  const int tid = threadIdx.x;
  const int lane = tid & 63;
  const int wave = tid >> 6;
  const int wr = wave >> 1, wc = wave & 1;
  const long m0 = (long)blockIdx.x * 128;
  const long n0 = (long)blockIdx.y * 128;

  f32x4 acc[4][4] = {};

  const int o0 = tid * 16;
  const int row0_ = o0 >> 6;
  const int colb0 = o0 & 63;

  auto stage = [&](int buf, int kt) {
    const long k0 = (long)kt * 32;
    const char* Ab = (const char*)A;
    const char* Bb = (const char*)B;
    gload_lds16(Ab + ((m0 + row0_) * K + k0) * 2 + colb0,      (char*)&sA[buf][0] + o0);
    gload_lds16(Ab + ((m0 + row0_ + 64) * K + k0) * 2 + colb0, (char*)&sA[buf][0] + o0 + 4096);
    gload_lds16(Bb + ((n0 + row0_) * K + k0) * 2 + colb0,      (char*)&sB[buf][0] + o0);
    gload_lds16(Bb + ((n0 + row0_ + 64) * K + k0) * 2 + colb0, (char*)&sB[buf][0] + o0 + 4096);
  };

  const int nk = K >> 5;
  stage(0, 0);
  __syncthreads();
  int cur = 0;
  const int kq = (lane >> 4) * 8;
  const int rA = wr * 64 + (lane & 15);
  const int rB = wc * 64 + (lane & 15);

  for (int kt = 0; kt < nk; ++kt) {
    if (kt + 1 < nk) stage(cur ^ 1, kt + 1);
    f16x8 af[4], bfr[4];
#pragma unroll
    for (int m = 0; m < 4; ++m)
      af[m] = *(const f16x8*)&sA[cur][(rA + m * 16) * 32 + kq];
#pragma unroll
    for (int n = 0; n < 4; ++n)
      bfr[n] = *(const f16x8*)&sB[cur][(rB + n * 16) * 32 + kq];
#pragma unroll
    for (int m = 0; m < 4; ++m)
#pragma unroll
      for (int n = 0; n < 4; ++n)
        acc[m][n] = __builtin_amdgcn_mfma_f32_16x16x32_f16(af[m], bfr[n], acc[m][n], 0, 0, 0);
    __syncthreads();
    cur ^= 1;
  }

  const long rbase = m0 + wr * 64 + ((lane >> 4) << 2);
  const long cbase = n0 + wc * 64 + (lane & 15);
#pragma unroll
  for (int m = 0; m < 4; ++m)
#pragma unroll
    for (int n = 0; n < 4; ++n)
#pragma unroll
      for (int r = 0; r < 4; ++r) {
        long row = rbase + m * 16 + r;
        long col = cbase + n * 16;
        C[row * N + col] = acc[m][n][r];
      }
}

// ---------------- launch ----------------
extern "C" void kernel_launch(void* const* d_in, const int* in_sizes, int n_in,
                              void* d_out, int out_size, void* d_ws, size_t ws_size,
                              hipStream_t stream) {
  const float* x     = (const float*)d_in[0];
  const float* w_qkv = (const float*)d_in[1];
  const float* w_out = (const float*)d_in[2];
  float* out = (float*)d_out;
  char* ws = (char*)d_ws;

  unsigned short* xb    = (unsigned short*)(ws + 0);           // 16 MB
  unsigned short* attnb = xb;                                  // alias (x dead)
  unsigned short* wqkvb = (unsigned short*)(ws + 16777216);    //  6 MB
  unsigned short* woutb = (unsigned short*)(ws + 23068672);    //  2 MB
  unsigned short* Qh    = (unsigned short*)(ws + 25165824);    // 16 MB
  unsigned short* Kh    = (unsigned short*)(ws + 41943040);    // 16 MB
  unsigned short* Vt    = (unsigned short*)(ws + 58720256);    // 16 MB
  float2*         tab   = (float2*)(ws + 75497472);            // 512 KB

  cvt_f16_kernel<<<2048, 256, 0, stream>>>(x, xb, NROWS * 1024 / 4);
  cvt_f16_kernel<<<1024, 256, 0, stream>>>(w_qkv, wqkvb, 3072 * 1024 / 4);
  cvt_f16_kernel<<<512, 256, 0, stream>>>(w_out, woutb, 1024 * 1024 / 4);
  sincos_kernel<<<SEQ * 32 / 256, 256, 0, stream>>>(tab);

  gemm_qkv_f16<<<dim3(64, 24), 256, 0, stream>>>(xb, wqkvb, tab, Qh, Kh, Vt);
  attn_kernel<<<dim3(SEQ / 256, 64), 512, 0, stream>>>(Qh, Kh, Vt, attnb);
  gemm_out_f16<<<dim3(64, 8), 256, 0, stream>>>(attnb, woutb, out, NROWS, 1024, 1024);
}

// Round 6
// 241.616 us; speedup vs baseline: 3.7877x; 1.0505x over previous
//
#include <hip/hip_runtime.h>
#include <stdint.h>
#include <math.h>

#define NHEAD 16
#define HDIM 64
#define BATCH 4
#define SEQ 2048
#define NROWS (BATCH*SEQ)   /* 8192 */
#define LOG2E 1.4426950408889634f

typedef _Float16 f16x8 __attribute__((ext_vector_type(8)));
typedef _Float16 f16x4 __attribute__((ext_vector_type(4)));
typedef __fp16 h16x2 __attribute__((ext_vector_type(2)));
typedef float f32x4 __attribute__((ext_vector_type(4)));
typedef float f32x16 __attribute__((ext_vector_type(16)));
typedef unsigned int u32x4 __attribute__((ext_vector_type(4)));

typedef const __attribute__((address_space(1))) unsigned int* gas_ptr;
typedef __attribute__((address_space(3))) unsigned int* las_ptr;

__device__ __forceinline__ void gload_lds16(const void* g, void* l) {
  __builtin_amdgcn_global_load_lds((gas_ptr)g, (las_ptr)l, 16, 0, 0);
}

__device__ __forceinline__ float exp2_fast(float x) {
  float r; asm("v_exp_f32 %0, %1" : "=v"(r) : "v"(x)); return r;
}

__device__ __forceinline__ unsigned pku(float a, float b) {
  h16x2 p = __builtin_amdgcn_cvt_pkrtz(a, b);
  return __builtin_bit_cast(unsigned, p);
}

// ---------------- fp32 -> fp16 convert ----------------
__global__ void cvt_f16_kernel(const float* __restrict__ in,
                               unsigned short* __restrict__ out, int n4) {
  int stride = gridDim.x * blockDim.x;
  for (int i = blockIdx.x * blockDim.x + threadIdx.x; i < n4; i += stride) {
    float4 v = ((const float4*)in)[i];
    f16x4 h;
    h[0] = (_Float16)v.x; h[1] = (_Float16)v.y;
    h[2] = (_Float16)v.z; h[3] = (_Float16)v.w;
    ((f16x4*)out)[i] = h;
  }
}

// ---------------- sincos table [SEQ][32] ----------------
__global__ void sincos_kernel(float2* __restrict__ tab) {
  int idx = blockIdx.x * blockDim.x + threadIdx.x;  // SEQ*32 = 65536
  int s = idx >> 5, i = idx & 31;
  float theta = powf(10000.0f, (float)i / 32.0f);
  float ang = (float)s / theta;
  tab[idx] = make_float2(sinf(ang), cosf(ang));
}

// ---------------- QKV GEMM (fp16) with fused RoPE + scatter epilogue ------
__global__ __launch_bounds__(256)
void gemm_qkv_f16(const unsigned short* __restrict__ A,
                  const unsigned short* __restrict__ B,
                  const float2* __restrict__ tab,
                  unsigned short* __restrict__ Qh,
                  unsigned short* __restrict__ Kh,
                  unsigned short* __restrict__ Vt) {
  const int K = 1024, N = 3072, nk = K >> 5;
  __shared__ unsigned short sA[2][128 * 32];
  __shared__ unsigned short sB[2][128 * 32];
  const int tid = threadIdx.x;
  const int lane = tid & 63;
  const int wave = tid >> 6;
  const int wr = wave >> 1, wc = wave & 1;
  const long m0 = (long)blockIdx.x * 128;
  const long n0 = (long)blockIdx.y * 128;

  f32x4 acc[4][4] = {};

  const int o0 = tid * 16;
  const int row0_ = o0 >> 6;
  const int colb0 = o0 & 63;

  auto stage = [&](int buf, int kt) {
    const long k0 = (long)kt * 32;
    const char* Ab = (const char*)A;
    const char* Bb = (const char*)B;
    gload_lds16(Ab + ((m0 + row0_) * K + k0) * 2 + colb0,      (char*)&sA[buf][0] + o0);
    gload_lds16(Ab + ((m0 + row0_ + 64) * K + k0) * 2 + colb0, (char*)&sA[buf][0] + o0 + 4096);
    gload_lds16(Bb + ((n0 + row0_) * K + k0) * 2 + colb0,      (char*)&sB[buf][0] + o0);
    gload_lds16(Bb + ((n0 + row0_ + 64) * K + k0) * 2 + colb0, (char*)&sB[buf][0] + o0 + 4096);
  };

  stage(0, 0);
  __syncthreads();
  int cur = 0;
  const int kq = (lane >> 4) * 8;
  const int rA = wr * 64 + (lane & 15);
  const int rB = wc * 64 + (lane & 15);

  for (int kt = 0; kt < nk; ++kt) {
    if (kt + 1 < nk) stage(cur ^ 1, kt + 1);
    f16x8 af[4], bfr[4];
#pragma unroll
    for (int m = 0; m < 4; ++m)
      af[m] = *(const f16x8*)&sA[cur][(rA + m * 16) * 32 + kq];
#pragma unroll
    for (int n = 0; n < 4; ++n)
      bfr[n] = *(const f16x8*)&sB[cur][(rB + n * 16) * 32 + kq];
#pragma unroll
    for (int m = 0; m < 4; ++m)
#pragma unroll
      for (int n = 0; n < 4; ++n)
        acc[m][n] = __builtin_amdgcn_mfma_f32_16x16x32_f16(af[m], bfr[n], acc[m][n], 0, 0, 0);
    __syncthreads();
    cur ^= 1;
  }

  // epilogue: fused RoPE + scatter
  const int lhi = lane >> 4, llo = lane & 15;
  const long rbase = m0 + wr * 64 + (lhi << 2);
  const long cbase = n0 + wc * 64 + llo;
#pragma unroll
  for (int m = 0; m < 4; ++m)
#pragma unroll
    for (int n = 0; n < 4; ++n)
#pragma unroll
      for (int r = 0; r < 4; ++r) {
        int row = (int)(rbase + m * 16 + r);
        int col = (int)(cbase + n * 16);
        float v = acc[m][n][r];
        float p = __shfl_xor(v, 1, 64);   // partner within rope pair (col^1)
        int s = row & 2047, b = row >> 11;
        int h = col / 192, off = col % 192;
        int part = off >> 6, d = off & 63;
        long bh_ = b * 16 + h;
        if (part < 2) {
          float2 sc = tab[s * 32 + (d >> 1)];
          float rot = (d & 1) ? (v * sc.y + p * sc.x) : (v * sc.y - p * sc.x);
          long idx = (bh_ * SEQ + s) * 64 + d;
          if (part == 0) ((_Float16*)Qh)[idx] = (_Float16)(rot * LOG2E);
          else           ((_Float16*)Kh)[idx] = (_Float16)rot;
        } else {
          ((_Float16*)Vt)[(bh_ * 64 + d) * SEQ + s] = (_Float16)v;
        }
      }
}

// ---------------- flash attention: 32x32 MFMA, in-register P (T12) --------
// 8 waves x 32 q-rows. Swapped QK^T: mfma(K,Q) -> col=q (lane&31), rows=keys,
// key split across lane/lane^32. Softmax in-lane + 1 shfl. P -> PV B-operand
// via cvt_pkrtz + v_permlane32_swap (no LDS). PV: out^T = V^T x P^T.
__global__ __launch_bounds__(512, 3)
void attn_kernel(const unsigned short* __restrict__ Qh,
                 const unsigned short* __restrict__ Kh,
                 const unsigned short* __restrict__ Vt,
                 unsigned short* __restrict__ AOut) {
  __shared__ unsigned short sK[2][64 * 64];   // [key][dim], 16B-chunk-swizzled
  __shared__ unsigned short sV[2][64 * 64];   // [dim][key], 16B-chunk-swizzled

  const int tid = threadIdx.x;
  const int w = tid >> 6, lane = tid & 63;
  const int q32 = lane & 31, hi = lane >> 5;
  const int bh = blockIdx.y, b = bh >> 4, h = bh & 15;
  const int q = blockIdx.x * 256 + w * 32 + q32;

  // Q B-frags: lane holds Q[d = ds*16 + hi*8 + j][col=q]
  f16x8 aq[4];
#pragma unroll
  for (int ds = 0; ds < 4; ++ds)
    aq[ds] = *(const f16x8*)&Qh[((long)bh * SEQ + q) * 64 + ds * 16 + hi * 8];

  f32x16 acc0 = {}, acc1 = {};      // out^T tiles: d 0-31, 32-63 (col=q)
  float mrow = -INFINITY, lrow = 0.f;

  // LDS frag offsets: row = t*32+q32, 16B chunk c = s*2+hi, swizzle c^(row&7)
  const int r7 = q32 & 7;
  int off[2][4];
#pragma unroll
  for (int t = 0; t < 2; ++t)
#pragma unroll
    for (int s = 0; s < 4; ++s)
      off[t][s] = (t * 32 + q32) * 64 + (((s * 2 + hi) ^ r7) << 3);

  // staging: thread tid stages 16B chunk tid, source pre-swizzled
  const int cr = tid >> 3, cp = tid & 7, cps = cp ^ (cr & 7);
  const long kSrc0 = ((long)bh * SEQ + cr) * 64 + cps * 8;   // + kt*4096
  const long vSrc0 = ((long)bh * 64 + cr) * SEQ + cps * 8;   // + kt*64

  auto stage = [&](int buf, int kt) {
    gload_lds16(&Kh[kSrc0 + (long)kt * 4096], (char*)&sK[buf][0] + tid * 16);
    gload_lds16(&Vt[vSrc0 + (long)kt * 64],   (char*)&sV[buf][0] + tid * 16);
  };

  stage(0, 0);
  __syncthreads();

#define MKPA(dst, S, R0) {                                        \
    unsigned A0 = pku(S[R0 + 0], S[R0 + 1]);                      \
    unsigned A1 = pku(S[R0 + 2], S[R0 + 3]);                      \
    unsigned B0 = pku(S[R0 + 4], S[R0 + 5]);                      \
    unsigned B1 = pku(S[R0 + 6], S[R0 + 7]);                      \
    asm("v_permlane32_swap_b32 %0, %1" : "+v"(A0), "+v"(B0));     \
    asm("v_permlane32_swap_b32 %0, %1" : "+v"(A1), "+v"(B1));     \
    u32x4 tt; tt[0] = A0; tt[1] = A1; tt[2] = B0; tt[3] = B1;     \
    dst = __builtin_bit_cast(f16x8, tt); }

#pragma unroll 2
  for (int kt = 0; kt < SEQ / 64; ++kt) {
    const int cur = kt & 1;
    if (kt + 1 < SEQ / 64) stage(cur ^ 1, kt + 1);
    const unsigned short* Kb = &sK[cur][0];
    const unsigned short* Vb = &sV[cur][0];

    // QK^T: scores (log2-domain), rows=keys (crow), col=q
    f32x16 s0v = {}, s1v = {};
    __builtin_amdgcn_s_setprio(1);
#pragma unroll
    for (int ds = 0; ds < 4; ++ds) {
      f16x8 k0 = *(const f16x8*)&Kb[off[0][ds]];
      f16x8 k1 = *(const f16x8*)&Kb[off[1][ds]];
      s0v = __builtin_amdgcn_mfma_f32_32x32x16_f16(k0, aq[ds], s0v, 0, 0, 0);
      s1v = __builtin_amdgcn_mfma_f32_32x32x16_f16(k1, aq[ds], s1v, 0, 0, 0);
    }
    __builtin_amdgcn_s_setprio(0);

    // row max over 32 in-lane + cross-hi
    float ta[16];
#pragma unroll
    for (int r = 0; r < 16; ++r) ta[r] = fmaxf(s0v[r], s1v[r]);
#pragma unroll
    for (int d = 8; d > 0; d >>= 1)
#pragma unroll
      for (int r = 0; r < d; ++r) ta[r] = fmaxf(ta[r], ta[r + d]);
    float tmax = fmaxf(ta[0], __shfl_xor(ta[0], 32, 64));

    // defer-max (THR = 8 in log2 units)
    if (__any(tmax > mrow + 8.0f)) {
      float mnew = fmaxf(mrow, tmax);
      float al = exp2_fast(mrow - mnew);
      mrow = mnew;
#pragma unroll
      for (int r = 0; r < 16; ++r) { acc0[r] *= al; acc1[r] *= al; }
      lrow *= al;
    }
    const float mr = mrow;

    // P = 2^(s - m) in-place
#pragma unroll
    for (int r = 0; r < 16; ++r) {
      s0v[r] = exp2_fast(s0v[r] - mr);
      s1v[r] = exp2_fast(s1v[r] - mr);
    }

    // l row-sum: in-lane tree + cross-hi
    float sa[16];
#pragma unroll
    for (int r = 0; r < 16; ++r) sa[r] = s0v[r] + s1v[r];
#pragma unroll
    for (int d = 8; d > 0; d >>= 1)
#pragma unroll
      for (int r = 0; r < d; ++r) sa[r] = sa[r] + sa[r + d];
    lrow += sa[0] + __shfl_xor(sa[0], 32, 64);

    // P -> PV B-frags (keys ks*16 + hi*8 + j, col=q), pure registers
    f16x8 pa[4];
    MKPA(pa[0], s0v, 0);
    MKPA(pa[1], s0v, 8);
    MKPA(pa[2], s1v, 0);
    MKPA(pa[3], s1v, 8);

    // PV: A = V^T frag (row=d, k=key), B = P frag
    __builtin_amdgcn_s_setprio(1);
#pragma unroll
    for (int ks = 0; ks < 4; ++ks) {
      f16x8 v0 = *(const f16x8*)&Vb[off[0][ks]];
      f16x8 v1 = *(const f16x8*)&Vb[off[1][ks]];
      acc0 = __builtin_amdgcn_mfma_f32_32x32x16_f16(v0, pa[ks], acc0, 0, 0, 0);
      acc1 = __builtin_amdgcn_mfma_f32_32x32x16_f16(v1, pa[ks], acc1, 0, 0, 0);
    }
    __builtin_amdgcn_s_setprio(0);
    __syncthreads();
  }

  // epilogue: out[q][d], d = dt*32 + rg*8 + hi*4 + e
  float inv = 1.f / lrow;
  const long obase = ((long)b * SEQ + q) * 1024 + h * 64;
#define EPI(ACCV, DT)                                              \
  {                                                                \
    _Pragma("unroll")                                              \
    for (int rg = 0; rg < 4; ++rg) {                               \
      f16x4 o;                                                     \
      _Pragma("unroll")                                            \
      for (int e = 0; e < 4; ++e)                                  \
        o[e] = (_Float16)(ACCV[rg * 4 + e] * inv);                 \
      *(f16x4*)&AOut[obase + DT * 32 + rg * 8 + hi * 4] = o;       \
    }                                                              \
  }
  EPI(acc0, 0);
  EPI(acc1, 1);
}

// ---------------- out-proj GEMM: C[M][N] = A[M][K] * B[N][K]^T, fp32 out ---
__global__ __launch_bounds__(256)
void gemm_out_f16(const unsigned short* __restrict__ A,
                  const unsigned short* __restrict__ B,
                  float* __restrict__ C, int M, int N, int K) {
  __shared__ unsigned short sA[2][128 * 32];
  __shared__ unsigned short sB[2][128 * 32];
  const int tid = threadIdx.x;
  const int lane = tid & 63;
  const int wave = tid >> 6;
  const int wr = wave >> 1, wc = wave & 1;
  const long m0 = (long)blockIdx.x * 128;
  const long n0 = (long)blockIdx.y * 128;

  f32x4 acc[4][4] = {};

  const int o0 = tid * 16;
  const int row0_ = o0 >> 6;
  const int colb0 = o0 & 63;

  auto stage = [&](int buf, int kt) {
    const long k0 = (long)kt * 32;
    const char* Ab = (const char*)A;
    const char* Bb = (const char*)B;
    gload_lds16(Ab + ((m0 + row0_) * K + k0) * 2 + colb0,      (char*)&sA[buf][0] + o0);
    gload_lds16(Ab + ((m0 + row0_ + 64) * K + k0) * 2 + colb0, (char*)&sA[buf][0] + o0 + 4096);
    gload_lds16(Bb + ((n0 + row0_) * K + k0) * 2 + colb0,      (char*)&sB[buf][0] + o0);
    gload_lds16(Bb + ((n0 + row0_ + 64) * K + k0) * 2 + colb0, (char*)&sB[buf][0] + o0 + 4096);
  };

  const int nk = K >> 5;
  stage(0, 0);
  __syncthreads();
  int cur = 0;
  const int kq = (lane >> 4) * 8;
  const int rA = wr * 64 + (lane & 15);
  const int rB = wc * 64 + (lane & 15);

  for (int kt = 0; kt < nk; ++kt) {
    if (kt + 1 < nk) stage(cur ^ 1, kt + 1);
    f16x8 af[4], bfr[4];
#pragma unroll
    for (int m = 0; m < 4; ++m)
      af[m] = *(const f16x8*)&sA[cur][(rA + m * 16) * 32 + kq];
#pragma unroll
    for (int n = 0; n < 4; ++n)
      bfr[n] = *(const f16x8*)&sB[cur][(rB + n * 16) * 32 + kq];
#pragma unroll
    for (int m = 0; m < 4; ++m)
#pragma unroll
      for (int n = 0; n < 4; ++n)
        acc[m][n] = __builtin_amdgcn_mfma_f32_16x16x32_f16(af[m], bfr[n], acc[m][n], 0, 0, 0);
    __syncthreads();
    cur ^= 1;
  }

  const long rbase = m0 + wr * 64 + ((lane >> 4) << 2);
  const long cbase = n0 + wc * 64 + (lane & 15);
#pragma unroll
  for (int m = 0; m < 4; ++m)
#pragma unroll
    for (int n = 0; n < 4; ++n)
#pragma unroll
      for (int r = 0; r < 4; ++r) {
        long row = rbase + m * 16 + r;
        long col = cbase + n * 16;
        C[row * N + col] = acc[m][n][r];
      }
}

// ---------------- launch ----------------
extern "C" void kernel_launch(void* const* d_in, const int* in_sizes, int n_in,
                              void* d_out, int out_size, void* d_ws, size_t ws_size,
                              hipStream_t stream) {
  const float* x     = (const float*)d_in[0];
  const float* w_qkv = (const float*)d_in[1];
  const float* w_out = (const float*)d_in[2];
  float* out = (float*)d_out;
  char* ws = (char*)d_ws;

  unsigned short* xb    = (unsigned short*)(ws + 0);           // 16 MB
  unsigned short* attnb = xb;                                  // alias (x dead)
  unsigned short* wqkvb = (unsigned short*)(ws + 16777216);    //  6 MB
  unsigned short* woutb = (unsigned short*)(ws + 23068672);    //  2 MB
  unsigned short* Qh    = (unsigned short*)(ws + 25165824);    // 16 MB
  unsigned short* Kh    = (unsigned short*)(ws + 41943040);    // 16 MB
  unsigned short* Vt    = (unsigned short*)(ws + 58720256);    // 16 MB
  float2*         tab   = (float2*)(ws + 75497472);            // 512 KB

  cvt_f16_kernel<<<2048, 256, 0, stream>>>(x, xb, NROWS * 1024 / 4);
  cvt_f16_kernel<<<1024, 256, 0, stream>>>(w_qkv, wqkvb, 3072 * 1024 / 4);
  cvt_f16_kernel<<<512, 256, 0, stream>>>(w_out, woutb, 1024 * 1024 / 4);
  sincos_kernel<<<SEQ * 32 / 256, 256, 0, stream>>>(tab);

  gemm_qkv_f16<<<dim3(64, 24), 256, 0, stream>>>(xb, wqkvb, tab, Qh, Kh, Vt);
  attn_kernel<<<dim3(SEQ / 256, 64), 512, 0, stream>>>(Qh, Kh, Vt, attnb);
  gemm_out_f16<<<dim3(64, 8), 256, 0, stream>>>(attnb, woutb, out, NROWS, 1024, 1024);
}

// Round 7
// 213.068 us; speedup vs baseline: 4.2952x; 1.1340x over previous
//
#include <hip/hip_runtime.h>
#include <stdint.h>
#include <math.h>

#define NHEAD 16
#define HDIM 64
#define BATCH 4
#define SEQ 2048
#define NROWS (BATCH*SEQ)   /* 8192 */
#define LOG2E 1.4426950408889634f

typedef _Float16 f16x8 __attribute__((ext_vector_type(8)));
typedef _Float16 f16x4 __attribute__((ext_vector_type(4)));
typedef __fp16 h16x2 __attribute__((ext_vector_type(2)));
typedef float f32x4 __attribute__((ext_vector_type(4)));
typedef float f32x16 __attribute__((ext_vector_type(16)));
typedef unsigned int u32x4 __attribute__((ext_vector_type(4)));

typedef const __attribute__((address_space(1))) unsigned int* gas_ptr;
typedef __attribute__((address_space(3))) unsigned int* las_ptr;

__device__ __forceinline__ void gload_lds16(const void* g, void* l) {
  __builtin_amdgcn_global_load_lds((gas_ptr)g, (las_ptr)l, 16, 0, 0);
}

__device__ __forceinline__ float exp2_fast(float x) {
  float r; asm("v_exp_f32 %0, %1" : "=v"(r) : "v"(x)); return r;
}

__device__ __forceinline__ unsigned pku(float a, float b) {
  h16x2 p = __builtin_amdgcn_cvt_pkrtz(a, b);
  return __builtin_bit_cast(unsigned, p);
}

// ---------------- fp32 -> fp16 convert ----------------
__global__ void cvt_f16_kernel(const float* __restrict__ in,
                               unsigned short* __restrict__ out, int n4) {
  int stride = gridDim.x * blockDim.x;
  for (int i = blockIdx.x * blockDim.x + threadIdx.x; i < n4; i += stride) {
    float4 v = ((const float4*)in)[i];
    f16x4 h;
    h[0] = (_Float16)v.x; h[1] = (_Float16)v.y;
    h[2] = (_Float16)v.z; h[3] = (_Float16)v.w;
    ((f16x4*)out)[i] = h;
  }
}

// ---------------- sincos table [SEQ][32] ----------------
__global__ void sincos_kernel(float2* __restrict__ tab) {
  int idx = blockIdx.x * blockDim.x + threadIdx.x;  // SEQ*32 = 65536
  int s = idx >> 5, i = idx & 31;
  float theta = powf(10000.0f, (float)i / 32.0f);
  float ang = (float)s / theta;
  tab[idx] = make_float2(sinf(ang), cosf(ang));
}

// ---------------- QKV GEMM (fp16, BK=64, T2 swizzle) + fused RoPE scatter --
// A[8192][1024], B[3072][1024]; C = A*B^T. Epilogue: RoPE (fp32);
// Q scaled by log2(e); scatter to Qh/Kh [bh][s][64], Vt [bh][64][s].
__global__ __launch_bounds__(256)
void gemm_qkv_f16(const unsigned short* __restrict__ A,
                  const unsigned short* __restrict__ B,
                  const float2* __restrict__ tab,
                  unsigned short* __restrict__ Qh,
                  unsigned short* __restrict__ Kh,
                  unsigned short* __restrict__ Vt) {
  const int K = 1024, nk = K >> 6;            // 16 K-tiles of 64
  __shared__ unsigned short sA[2][128 * 64];  // [row][64 elems], chunk-swizzled
  __shared__ unsigned short sB[2][128 * 64];
  const int tid = threadIdx.x;
  const int lane = tid & 63;
  const int wave = tid >> 6;
  const int wr = wave >> 1, wc = wave & 1;
  const long m0 = (long)blockIdx.x * 128;
  const long n0 = (long)blockIdx.y * 128;

  f32x4 acc[4][4] = {};

  auto stage = [&](int buf, int kt) {
    const long k0 = (long)kt * 64;
    const char* Ab = (const char*)A;
    const char* Bb = (const char*)B;
#pragma unroll
    for (int qd = 0; qd < 4; ++qd) {
      int o = qd * 4096 + tid * 16;            // byte off in 16KB tile
      int row = o >> 7;                        // 128B per row
      int colb = (((o >> 4) & 7) ^ (row & 7)) << 4;   // pre-swizzled source chunk
      gload_lds16(Ab + ((m0 + row) * K + k0) * 2 + colb, (char*)&sA[buf][0] + o);
      gload_lds16(Bb + ((n0 + row) * K + k0) * 2 + colb, (char*)&sB[buf][0] + o);
    }
  };

  const int lhi = lane >> 4, llo = lane & 15;
  const int rA = wr * 64 + llo;
  const int rB = wc * 64 + llo;
  // swizzled chunk offsets (elems) for k-step s: chunk = (s*4+lhi) ^ (llo&7)
  int chsw[2];
#pragma unroll
  for (int s = 0; s < 2; ++s) chsw[s] = (((s * 4 + lhi) ^ (llo & 7)) << 3);

  stage(0, 0);
  __syncthreads();
  int cur = 0;

  for (int kt = 0; kt < nk; ++kt) {
    if (kt + 1 < nk) stage(cur ^ 1, kt + 1);
    f16x8 af[2][4], bfr[2][4];
#pragma unroll
    for (int s = 0; s < 2; ++s)
#pragma unroll
      for (int m = 0; m < 4; ++m)
        af[s][m] = *(const f16x8*)&sA[cur][(rA + m * 16) * 64 + chsw[s]];
#pragma unroll
    for (int s = 0; s < 2; ++s)
#pragma unroll
      for (int n = 0; n < 4; ++n)
        bfr[s][n] = *(const f16x8*)&sB[cur][(rB + n * 16) * 64 + chsw[s]];
#pragma unroll
    for (int m = 0; m < 4; ++m)
#pragma unroll
      for (int n = 0; n < 4; ++n) {
        acc[m][n] = __builtin_amdgcn_mfma_f32_16x16x32_f16(af[0][m], bfr[0][n], acc[m][n], 0, 0, 0);
        acc[m][n] = __builtin_amdgcn_mfma_f32_16x16x32_f16(af[1][m], bfr[1][n], acc[m][n], 0, 0, 0);
      }
    __syncthreads();
    cur ^= 1;
  }

  // epilogue: fused RoPE + scatter, per-n hoisted address math
  const int rb0 = (int)m0 + wr * 64 + lhi * 4;
  const int bidx = rb0 >> 11;          // batch, constant per block
  const int s0 = rb0 & 2047;
#pragma unroll
  for (int n = 0; n < 4; ++n) {
    const int col = (int)n0 + wc * 64 + llo + n * 16;
    const int h = col / 192;
    const int off = col - h * 192;
    const int part = off >> 6;
    const int d = off & 63;
    const long bh_ = (long)(bidx * 16 + h);
    if (part < 2) {
      _Float16* dst = (_Float16*)(part == 0 ? Qh : Kh) + bh_ * SEQ * 64 + d;
      const float qs = (part == 0) ? LOG2E : 1.0f;
      const float2* tp = tab + (d >> 1);
      const int sgn = d & 1;
#pragma unroll
      for (int m = 0; m < 4; ++m)
#pragma unroll
        for (int r = 0; r < 4; ++r) {
          int s = s0 + m * 16 + r;
          float v = acc[m][n][r];
          float p = __shfl_xor(v, 1, 64);    // partner (col^1), same part
          float2 sc = tp[s * 32];
          float rot = sgn ? (v * sc.y + p * sc.x) : (v * sc.y - p * sc.x);
          dst[(long)s * 64] = (_Float16)(rot * qs);
        }
    } else {
      _Float16* dst = (_Float16*)Vt + (bh_ * 64 + d) * SEQ;
#pragma unroll
      for (int m = 0; m < 4; ++m)
#pragma unroll
        for (int r = 0; r < 4; ++r)
          dst[s0 + m * 16 + r] = (_Float16)acc[m][n][r];
    }
  }
}

// ---------------- flash attention: 32x32 MFMA, in-register P (T12) --------
__global__ __launch_bounds__(512, 3)
void attn_kernel(const unsigned short* __restrict__ Qh,
                 const unsigned short* __restrict__ Kh,
                 const unsigned short* __restrict__ Vt,
                 unsigned short* __restrict__ AOut) {
  __shared__ unsigned short sK[2][64 * 64];   // [key][dim], 16B-chunk-swizzled
  __shared__ unsigned short sV[2][64 * 64];   // [dim][key], 16B-chunk-swizzled

  const int tid = threadIdx.x;
  const int w = tid >> 6, lane = tid & 63;
  const int q32 = lane & 31, hi = lane >> 5;
  const int bh = blockIdx.y, b = bh >> 4, h = bh & 15;
  const int q = blockIdx.x * 256 + w * 32 + q32;

  f16x8 aq[4];
#pragma unroll
  for (int ds = 0; ds < 4; ++ds)
    aq[ds] = *(const f16x8*)&Qh[((long)bh * SEQ + q) * 64 + ds * 16 + hi * 8];

  f32x16 acc0 = {}, acc1 = {};      // out^T tiles: d 0-31, 32-63 (col=q)
  float mrow = -INFINITY, lrow = 0.f;

  const int r7 = q32 & 7;
  int off[2][4];
#pragma unroll
  for (int t = 0; t < 2; ++t)
#pragma unroll
    for (int s = 0; s < 4; ++s)
      off[t][s] = (t * 32 + q32) * 64 + (((s * 2 + hi) ^ r7) << 3);

  const int cr = tid >> 3, cp = tid & 7, cps = cp ^ (cr & 7);
  const long kSrc0 = ((long)bh * SEQ + cr) * 64 + cps * 8;   // + kt*4096
  const long vSrc0 = ((long)bh * 64 + cr) * SEQ + cps * 8;   // + kt*64

  auto stage = [&](int buf, int kt) {
    gload_lds16(&Kh[kSrc0 + (long)kt * 4096], (char*)&sK[buf][0] + tid * 16);
    gload_lds16(&Vt[vSrc0 + (long)kt * 64],   (char*)&sV[buf][0] + tid * 16);
  };

  stage(0, 0);
  __syncthreads();

#define MKPA(dst, S, R0) {                                        \
    unsigned A0 = pku(S[R0 + 0], S[R0 + 1]);                      \
    unsigned A1 = pku(S[R0 + 2], S[R0 + 3]);                      \
    unsigned B0 = pku(S[R0 + 4], S[R0 + 5]);                      \
    unsigned B1 = pku(S[R0 + 6], S[R0 + 7]);                      \
    asm("v_permlane32_swap_b32 %0, %1" : "+v"(A0), "+v"(B0));     \
    asm("v_permlane32_swap_b32 %0, %1" : "+v"(A1), "+v"(B1));     \
    u32x4 tt; tt[0] = A0; tt[1] = A1; tt[2] = B0; tt[3] = B1;     \
    dst = __builtin_bit_cast(f16x8, tt); }

#pragma unroll 2
  for (int kt = 0; kt < SEQ / 64; ++kt) {
    const int cur = kt & 1;
    if (kt + 1 < SEQ / 64) stage(cur ^ 1, kt + 1);
    const unsigned short* Kb = &sK[cur][0];
    const unsigned short* Vb = &sV[cur][0];

    f32x16 s0v = {}, s1v = {};
    __builtin_amdgcn_s_setprio(1);
#pragma unroll
    for (int ds = 0; ds < 4; ++ds) {
      f16x8 k0 = *(const f16x8*)&Kb[off[0][ds]];
      f16x8 k1 = *(const f16x8*)&Kb[off[1][ds]];
      s0v = __builtin_amdgcn_mfma_f32_32x32x16_f16(k0, aq[ds], s0v, 0, 0, 0);
      s1v = __builtin_amdgcn_mfma_f32_32x32x16_f16(k1, aq[ds], s1v, 0, 0, 0);
    }
    __builtin_amdgcn_s_setprio(0);

    float ta[16];
#pragma unroll
    for (int r = 0; r < 16; ++r) ta[r] = fmaxf(s0v[r], s1v[r]);
#pragma unroll
    for (int d = 8; d > 0; d >>= 1)
#pragma unroll
      for (int r = 0; r < d; ++r) ta[r] = fmaxf(ta[r], ta[r + d]);
    float tmax = fmaxf(ta[0], __shfl_xor(ta[0], 32, 64));

    if (__any(tmax > mrow + 8.0f)) {
      float mnew = fmaxf(mrow, tmax);
      float al = exp2_fast(mrow - mnew);
      mrow = mnew;
#pragma unroll
      for (int r = 0; r < 16; ++r) { acc0[r] *= al; acc1[r] *= al; }
      lrow *= al;
    }
    const float mr = mrow;

#pragma unroll
    for (int r = 0; r < 16; ++r) {
      s0v[r] = exp2_fast(s0v[r] - mr);
      s1v[r] = exp2_fast(s1v[r] - mr);
    }

    float sa[16];
#pragma unroll
    for (int r = 0; r < 16; ++r) sa[r] = s0v[r] + s1v[r];
#pragma unroll
    for (int d = 8; d > 0; d >>= 1)
#pragma unroll
      for (int r = 0; r < d; ++r) sa[r] = sa[r] + sa[r + d];
    lrow += sa[0] + __shfl_xor(sa[0], 32, 64);

    f16x8 pa[4];
    MKPA(pa[0], s0v, 0);
    MKPA(pa[1], s0v, 8);
    MKPA(pa[2], s1v, 0);
    MKPA(pa[3], s1v, 8);

    __builtin_amdgcn_s_setprio(1);
#pragma unroll
    for (int ks = 0; ks < 4; ++ks) {
      f16x8 v0 = *(const f16x8*)&Vb[off[0][ks]];
      f16x8 v1 = *(const f16x8*)&Vb[off[1][ks]];
      acc0 = __builtin_amdgcn_mfma_f32_32x32x16_f16(v0, pa[ks], acc0, 0, 0, 0);
      acc1 = __builtin_amdgcn_mfma_f32_32x32x16_f16(v1, pa[ks], acc1, 0, 0, 0);
    }
    __builtin_amdgcn_s_setprio(0);
    __syncthreads();
  }

  float inv = 1.f / lrow;
  const long obase = ((long)b * SEQ + q) * 1024 + h * 64;
#define EPI(ACCV, DT)                                              \
  {                                                                \
    _Pragma("unroll")                                              \
    for (int rg = 0; rg < 4; ++rg) {                               \
      f16x4 o;                                                     \
      _Pragma("unroll")                                            \
      for (int e = 0; e < 4; ++e)                                  \
        o[e] = (_Float16)(ACCV[rg * 4 + e] * inv);                 \
      *(f16x4*)&AOut[obase + DT * 32 + rg * 8 + hi * 4] = o;       \
    }                                                              \
  }
  EPI(acc0, 0);
  EPI(acc1, 1);
}

// ---------------- out-proj GEMM (BK=64, T2 swizzle): fp32 out -------------
__global__ __launch_bounds__(256)
void gemm_out_f16(const unsigned short* __restrict__ A,
                  const unsigned short* __restrict__ B,
                  float* __restrict__ C, int M, int N, int K) {
  __shared__ unsigned short sA[2][128 * 64];
  __shared__ unsigned short sB[2][128 * 64];
  const int tid = threadIdx.x;
  const int lane = tid & 63;
  const int wave = tid >> 6;
  const int wr = wave >> 1, wc = wave & 1;
  const long m0 = (long)blockIdx.x * 128;
  const long n0 = (long)blockIdx.y * 128;

  f32x4 acc[4][4] = {};

  auto stage = [&](int buf, int kt) {
    const long k0 = (long)kt * 64;
    const char* Ab = (const char*)A;
    const char* Bb = (const char*)B;
#pragma unroll
    for (int qd = 0; qd < 4; ++qd) {
      int o = qd * 4096 + tid * 16;
      int row = o >> 7;
      int colb = (((o >> 4) & 7) ^ (row & 7)) << 4;
      gload_lds16(Ab + ((m0 + row) * K + k0) * 2 + colb, (char*)&sA[buf][0] + o);
      gload_lds16(Bb + ((n0 + row) * K + k0) * 2 + colb, (char*)&sB[buf][0] + o);
    }
  };

  const int lhi = lane >> 4, llo = lane & 15;
  const int rA = wr * 64 + llo;
  const int rB = wc * 64 + llo;
  int chsw[2];
#pragma unroll
  for (int s = 0; s < 2; ++s) chsw[s] = (((s * 4 + lhi) ^ (llo & 7)) << 3);

  const int nk = K >> 6;
  stage(0, 0);
  __syncthreads();
  int cur = 0;

  for (int kt = 0; kt < nk; ++kt) {
    if (kt + 1 < nk) stage(cur ^ 1, kt + 1);
    f16x8 af[2][4], bfr[2][4];
#pragma unroll
    for (int s = 0; s < 2; ++s)
#pragma unroll
      for (int m = 0; m < 4; ++m)
        af[s][m] = *(const f16x8*)&sA[cur][(rA + m * 16) * 64 + chsw[s]];
#pragma unroll
    for (int s = 0; s < 2; ++s)
#pragma unroll
      for (int n = 0; n < 4; ++n)
        bfr[s][n] = *(const f16x8*)&sB[cur][(rB + n * 16) * 64 + chsw[s]];
#pragma unroll
    for (int m = 0; m < 4; ++m)
#pragma unroll
      for (int n = 0; n < 4; ++n) {
        acc[m][n] = __builtin_amdgcn_mfma_f32_16x16x32_f16(af[0][m], bfr[0][n], acc[m][n], 0, 0, 0);
        acc[m][n] = __builtin_amdgcn_mfma_f32_16x16x32_f16(af[1][m], bfr[1][n], acc[m][n], 0, 0, 0);
      }
    __syncthreads();
    cur ^= 1;
  }

  const long rbase = m0 + wr * 64 + lhi * 4;
#pragma unroll
  for (int n = 0; n < 4; ++n) {
    const long col = n0 + wc * 64 + llo + n * 16;
#pragma unroll
    for (int m = 0; m < 4; ++m)
#pragma unroll
      for (int r = 0; r < 4; ++r)
        C[(rbase + m * 16 + r) * N + col] = acc[m][n][r];
  }
}

// ---------------- launch ----------------
extern "C" void kernel_launch(void* const* d_in, const int* in_sizes, int n_in,
                              void* d_out, int out_size, void* d_ws, size_t ws_size,
                              hipStream_t stream) {
  const float* x     = (const float*)d_in[0];
  const float* w_qkv = (const float*)d_in[1];
  const float* w_out = (const float*)d_in[2];
  float* out = (float*)d_out;
  char* ws = (char*)d_ws;

  unsigned short* xb    = (unsigned short*)(ws + 0);           // 16 MB
  unsigned short* attnb = xb;                                  // alias (x dead)
  unsigned short* wqkvb = (unsigned short*)(ws + 16777216);    //  6 MB
  unsigned short* woutb = (unsigned short*)(ws + 23068672);    //  2 MB
  unsigned short* Qh    = (unsigned short*)(ws + 25165824);    // 16 MB
  unsigned short* Kh    = (unsigned short*)(ws + 41943040);    // 16 MB
  unsigned short* Vt    = (unsigned short*)(ws + 58720256);    // 16 MB
  float2*         tab   = (float2*)(ws + 75497472);            // 512 KB

  cvt_f16_kernel<<<2048, 256, 0, stream>>>(x, xb, NROWS * 1024 / 4);
  cvt_f16_kernel<<<1024, 256, 0, stream>>>(w_qkv, wqkvb, 3072 * 1024 / 4);
  cvt_f16_kernel<<<512, 256, 0, stream>>>(w_out, woutb, 1024 * 1024 / 4);
  sincos_kernel<<<SEQ * 32 / 256, 256, 0, stream>>>(tab);

  gemm_qkv_f16<<<dim3(64, 24), 256, 0, stream>>>(xb, wqkvb, tab, Qh, Kh, Vt);
  attn_kernel<<<dim3(SEQ / 256, 64), 512, 0, stream>>>(Qh, Kh, Vt, attnb);
  gemm_out_f16<<<dim3(64, 8), 256, 0, stream>>>(attnb, woutb, out, NROWS, 1024, 1024);
}